// Round 2
// baseline (1949.849 us; speedup 1.0000x reference)
//
#include <hip/hip_runtime.h>

// HyperMixer fused kernel, MI355X (gfx950).
// Layout: x[B=2,S=4096,K=4,D=2048] f32, out[B,S,D] f32, W[24][8192] f32,
// scale[3], base[24]. Output = concat(y[B,S,K,D], collapsed[B,S,D]) f32.
//
// Design: 2 tokens per 256-thread block. Thread t owns f-slices
// f = t*4 + i*1024 (i=0..7) of each token's flat[8192] -> kept in registers.
// Phase A: sumsq + 24 raw dots (bf16 W from ws, converted by prep kernel),
// block reduce, 32 lanes compute sigmoid/softmax/sinkhorn weights.
// Phase B: outputs at d = dh*1024 + t*4 come entirely from the same regs
// (f = k*2048 + d  <=>  i = 2k + dh). x is read from HBM exactly once.

#define EPS 1e-6f
constexpr int K_ = 4, D_ = 2048, KD = 8192, NOUT = 24;
constexpr int NTOK = 2 * 4096;          // 8192 tokens
constexpr int TPB = 256;

static __device__ __forceinline__ unsigned short f2bf(float f) {
    unsigned int u = __float_as_uint(f);
    unsigned int r = (u + 0x7fffu + ((u >> 16) & 1u)) >> 16;
    return (unsigned short)r;
}

__global__ void conv_w_kernel(const float* __restrict__ W, unsigned short* __restrict__ Wb) {
    int i = (blockIdx.x * blockDim.x + threadIdx.x) * 4;
    float4 v = *reinterpret_cast<const float4*>(W + i);
    ushort4 u;
    u.x = f2bf(v.x); u.y = f2bf(v.y); u.z = f2bf(v.z); u.w = f2bf(v.w);
    *reinterpret_cast<ushort4*>(Wb + i) = u;
}

template <bool BW>
__global__ __launch_bounds__(TPB) void hypermix_kernel(
    const float* __restrict__ x, const float* __restrict__ outp,
    const unsigned short* __restrict__ Wb, const float* __restrict__ Wf,
    const float* __restrict__ scale, const float* __restrict__ base,
    float* __restrict__ y, float* __restrict__ coll)
{
    const int t = threadIdx.x;
    const int wave = t >> 6, lane = t & 63;
    const int bs0 = blockIdx.x * 2;

    __shared__ float red[4][52];   // [wave][tok*26 + o], o=24 is sumsq
    __shared__ float lg[2][26];    // block-summed raw dots + sumsq
    __shared__ float wts[2][24];   // 0..3 pre, 4..7 post, 8..23 comb[h][k]

    float4 xr[2][8];
    float acc[2][25];
#pragma unroll
    for (int tk = 0; tk < 2; ++tk)
#pragma unroll
        for (int o = 0; o < 25; ++o) acc[tk][o] = 0.f;

    const float* xb = x + (size_t)bs0 * KD + t * 4;

#pragma unroll
    for (int i = 0; i < 8; ++i) {
#pragma unroll
        for (int tk = 0; tk < 2; ++tk) {
            float4 v = *reinterpret_cast<const float4*>(xb + (size_t)tk * KD + i * 1024);
            xr[tk][i] = v;
            acc[tk][24] += v.x * v.x + v.y * v.y + v.z * v.z + v.w * v.w;
        }
        const int f = t * 4 + i * 1024;
#pragma unroll
        for (int o = 0; o < NOUT; ++o) {
            float wx, wy, wz, ww;
            if (BW) {
                uint2 u = *reinterpret_cast<const uint2*>(Wb + o * KD + f);
                wx = __uint_as_float(u.x << 16);
                wy = __uint_as_float(u.x & 0xffff0000u);
                wz = __uint_as_float(u.y << 16);
                ww = __uint_as_float(u.y & 0xffff0000u);
            } else {
                float4 w = *reinterpret_cast<const float4*>(Wf + o * KD + f);
                wx = w.x; wy = w.y; wz = w.z; ww = w.w;
            }
#pragma unroll
            for (int tk = 0; tk < 2; ++tk) {
                acc[tk][o] += xr[tk][i].x * wx + xr[tk][i].y * wy
                            + xr[tk][i].z * wz + xr[tk][i].w * ww;
            }
        }
    }

    // wave-level butterfly reduce of 50 accumulators
#pragma unroll
    for (int tk = 0; tk < 2; ++tk)
#pragma unroll
        for (int o = 0; o < 25; ++o) {
            float v = acc[tk][o];
#pragma unroll
            for (int m = 1; m < 64; m <<= 1) v += __shfl_xor(v, m, 64);
            if (lane == 0) red[wave][tk * 26 + o] = v;
        }
    __syncthreads();

    if (t < 50) {
        int tk = t / 25, o = t % 25;
        lg[tk][o] = red[0][tk * 26 + o] + red[1][tk * 26 + o]
                  + red[2][tk * 26 + o] + red[3][tk * 26 + o];
    }
    __syncthreads();

    if (t < 32) {
        int tk = t >> 4, idx = t & 15;
        float rms = rsqrtf(lg[tk][24] * (1.f / 8192.f) + EPS);
        float s0 = scale[0], s1 = scale[1], s2 = scale[2];
        // comb logits, softmax over k (idx&3), +eps
        float cl = lg[tk][8 + idx] * rms * s2 + base[8 + idx];
        float mx = fmaxf(cl, __shfl_xor(cl, 1, 64));
        mx = fmaxf(mx, __shfl_xor(mx, 2, 64));
        float e = expf(cl - mx);
        float se = e + __shfl_xor(e, 1, 64); se += __shfl_xor(se, 2, 64);
        float m = e / se + EPS;
        // sinkhorn: priming column norm (sum over h: xor 4,8), then 19x(row,col)
        float cs = m + __shfl_xor(m, 4, 64); cs += __shfl_xor(cs, 8, 64);
        m = m / (cs + EPS);
#pragma unroll
        for (int it = 0; it < 19; ++it) {
            float rs = m + __shfl_xor(m, 1, 64); rs += __shfl_xor(rs, 2, 64);
            m = m / (rs + EPS);
            cs = m + __shfl_xor(m, 4, 64); cs += __shfl_xor(cs, 8, 64);
            m = m / (cs + EPS);
        }
        wts[tk][8 + idx] = m;
        if (idx < 4) {
            float z = lg[tk][idx] * rms * s0 + base[idx];
            wts[tk][idx] = 1.f / (1.f + expf(-z)) + EPS;
        } else if (idx < 8) {
            float z = lg[tk][idx] * rms * s1 + base[idx];
            wts[tk][idx] = 2.f / (1.f + expf(-z));
        }
    }
    __syncthreads();

    // Phase B: outputs straight from registers
#pragma unroll
    for (int tk = 0; tk < 2; ++tk) {
        const int bs = bs0 + tk;
        float pre[4], post[4], cmb[4][4];
#pragma unroll
        for (int k = 0; k < 4; ++k) { pre[k] = wts[tk][k]; post[k] = wts[tk][4 + k]; }
#pragma unroll
        for (int h = 0; h < 4; ++h)
#pragma unroll
            for (int k = 0; k < 4; ++k) cmb[h][k] = wts[tk][8 + h * 4 + k];

#pragma unroll
        for (int dh = 0; dh < 2; ++dh) {
            const int dof = dh * 1024 + t * 4;
            float4 xk[4];
#pragma unroll
            for (int k = 0; k < 4; ++k) xk[k] = xr[tk][2 * k + dh];
            float4 ov = *reinterpret_cast<const float4*>(outp + (size_t)bs * D_ + dof);
            float4 cv;
            cv.x = pre[0] * xk[0].x + pre[1] * xk[1].x + pre[2] * xk[2].x + pre[3] * xk[3].x;
            cv.y = pre[0] * xk[0].y + pre[1] * xk[1].y + pre[2] * xk[2].y + pre[3] * xk[3].y;
            cv.z = pre[0] * xk[0].z + pre[1] * xk[1].z + pre[2] * xk[2].z + pre[3] * xk[3].z;
            cv.w = pre[0] * xk[0].w + pre[1] * xk[1].w + pre[2] * xk[2].w + pre[3] * xk[3].w;
            *reinterpret_cast<float4*>(coll + (size_t)bs * D_ + dof) = cv;
#pragma unroll
            for (int h = 0; h < 4; ++h) {
                float4 yv;
                yv.x = post[h] * ov.x + cmb[h][0] * xk[0].x + cmb[h][1] * xk[1].x + cmb[h][2] * xk[2].x + cmb[h][3] * xk[3].x;
                yv.y = post[h] * ov.y + cmb[h][0] * xk[0].y + cmb[h][1] * xk[1].y + cmb[h][2] * xk[2].y + cmb[h][3] * xk[3].y;
                yv.z = post[h] * ov.z + cmb[h][0] * xk[0].z + cmb[h][1] * xk[1].z + cmb[h][2] * xk[2].z + cmb[h][3] * xk[3].z;
                yv.w = post[h] * ov.w + cmb[h][0] * xk[0].w + cmb[h][1] * xk[1].w + cmb[h][2] * xk[2].w + cmb[h][3] * xk[3].w;
                *reinterpret_cast<float4*>(y + (size_t)bs * KD + h * D_ + dof) = yv;
            }
        }
    }
}

extern "C" void kernel_launch(void* const* d_in, const int* in_sizes, int n_in,
                              void* d_out, int out_size, void* d_ws, size_t ws_size,
                              hipStream_t stream) {
    const float* x     = (const float*)d_in[0];
    const float* outp  = (const float*)d_in[1];
    const float* W     = (const float*)d_in[2];
    const float* scale = (const float*)d_in[3];
    const float* base  = (const float*)d_in[4];
    float* y    = (float*)d_out;
    float* coll = y + (size_t)NTOK * KD;   // 67108864

    const size_t wb_bytes = (size_t)NOUT * KD * sizeof(unsigned short); // 384 KB
    if (ws_size >= wb_bytes) {
        unsigned short* Wb = (unsigned short*)d_ws;
        conv_w_kernel<<<NOUT * KD / (TPB * 4), TPB, 0, stream>>>(W, Wb);
        hypermix_kernel<true><<<NTOK / 2, TPB, 0, stream>>>(x, outp, Wb, W, scale, base, y, coll);
    } else {
        hypermix_kernel<false><<<NTOK / 2, TPB, 0, stream>>>(x, outp, nullptr, W, scale, base, y, coll);
    }
}

// Round 3
// 689.824 us; speedup vs baseline: 2.8266x; 2.8266x over previous
//
#include <hip/hip_runtime.h>

// HyperMixer fused kernel, MI355X (gfx950).
// x[B=2,S=4096,K=4,D=2048] f32, out[B,S,D] f32, W[24][8192] f32,
// scale[3], base[24]. Output = concat(y[B,S,K,D], collapsed[B,S,D]) f32.
//
// ONE token per 256-thread block (round-2 lesson: 2 tokens spilled at 256
// VGPRs -> 1.9 GB scratch traffic). Thread t owns f-slices f = t*4 + i*1024
// (i=0..7) of the token's flat[8192], kept in 32 VGPRs. Phase A: sumsq + 24
// raw dots against bf16 W (L2-resident, 384 KB, converted once by prep
// kernel), butterfly + LDS reduce, 16 lanes do sigmoid/softmax/sinkhorn.
// Phase B: outputs at d = dh*1024 + t*4 come from the same registers
// (f = k*2048 + d <=> i = 2k + dh). x is read from HBM exactly once.

#define EPS 1e-6f
constexpr int K_ = 4, D_ = 2048, KD = 8192, NOUT = 24;
constexpr int NTOK = 2 * 4096;          // 8192 tokens
constexpr int TPB = 256;

static __device__ __forceinline__ unsigned short f2bf(float f) {
    unsigned int u = __float_as_uint(f);
    unsigned int r = (u + 0x7fffu + ((u >> 16) & 1u)) >> 16;
    return (unsigned short)r;
}

__global__ void conv_w_kernel(const float* __restrict__ W, unsigned short* __restrict__ Wb) {
    int i = (blockIdx.x * blockDim.x + threadIdx.x) * 4;
    float4 v = *reinterpret_cast<const float4*>(W + i);
    ushort4 u;
    u.x = f2bf(v.x); u.y = f2bf(v.y); u.z = f2bf(v.z); u.w = f2bf(v.w);
    *reinterpret_cast<ushort4*>(Wb + i) = u;
}

template <bool BW>
__global__ __launch_bounds__(TPB) void hypermix_kernel(
    const float* __restrict__ x, const float* __restrict__ outp,
    const unsigned short* __restrict__ Wb, const float* __restrict__ Wf,
    const float* __restrict__ scale, const float* __restrict__ base,
    float* __restrict__ y, float* __restrict__ coll)
{
    const int t = threadIdx.x;
    const int wave = t >> 6, lane = t & 63;
    const int bs = blockIdx.x;

    __shared__ float red[4][25];   // [wave][o], o=24 is sumsq
    __shared__ float lg[25];       // block-summed raw dots + sumsq
    __shared__ float wts[24];      // 0..3 pre, 4..7 post, 8..23 comb[h][k]

    float4 xr[8];
    float acc[25];
#pragma unroll
    for (int o = 0; o < 25; ++o) acc[o] = 0.f;

    const float* xb = x + (size_t)bs * KD + t * 4;

#pragma unroll
    for (int i = 0; i < 8; ++i) {
        float4 v = *reinterpret_cast<const float4*>(xb + i * 1024);
        xr[i] = v;
        acc[24] += v.x * v.x + v.y * v.y + v.z * v.z + v.w * v.w;
        const int f = t * 4 + i * 1024;
#pragma unroll
        for (int o = 0; o < NOUT; ++o) {
            float wx, wy, wz, ww;
            if (BW) {
                uint2 u = *reinterpret_cast<const uint2*>(Wb + o * KD + f);
                wx = __uint_as_float(u.x << 16);
                wy = __uint_as_float(u.x & 0xffff0000u);
                wz = __uint_as_float(u.y << 16);
                ww = __uint_as_float(u.y & 0xffff0000u);
            } else {
                float4 w = *reinterpret_cast<const float4*>(Wf + o * KD + f);
                wx = w.x; wy = w.y; wz = w.z; ww = w.w;
            }
            acc[o] += v.x * wx + v.y * wy + v.z * wz + v.w * ww;
        }
    }

    // wave-level butterfly reduce of the 25 accumulators
#pragma unroll
    for (int o = 0; o < 25; ++o) {
        float v = acc[o];
#pragma unroll
        for (int m = 1; m < 64; m <<= 1) v += __shfl_xor(v, m, 64);
        if (lane == 0) red[wave][o] = v;
    }
    __syncthreads();

    if (t < 25) lg[t] = red[0][t] + red[1][t] + red[2][t] + red[3][t];
    __syncthreads();

    if (t < 16) {
        const int idx = t;                 // idx = h*4 + k
        float rms = rsqrtf(lg[24] * (1.f / 8192.f) + EPS);
        float s0 = scale[0], s1 = scale[1], s2 = scale[2];
        // comb logits; softmax over k (xor 1,2), +eps
        float cl = lg[8 + idx] * rms * s2 + base[8 + idx];
        float mx = fmaxf(cl, __shfl_xor(cl, 1, 64));
        mx = fmaxf(mx, __shfl_xor(mx, 2, 64));
        float e = expf(cl - mx);
        float se = e + __shfl_xor(e, 1, 64); se += __shfl_xor(se, 2, 64);
        float m = e / se + EPS;
        // sinkhorn: priming column norm (sum over h: xor 4,8), then 19x(row,col)
        float cs = m + __shfl_xor(m, 4, 64); cs += __shfl_xor(cs, 8, 64);
        m = m / (cs + EPS);
#pragma unroll
        for (int it = 0; it < 19; ++it) {
            float rs = m + __shfl_xor(m, 1, 64); rs += __shfl_xor(rs, 2, 64);
            m = m / (rs + EPS);
            cs = m + __shfl_xor(m, 4, 64); cs += __shfl_xor(cs, 8, 64);
            m = m / (cs + EPS);
        }
        wts[8 + idx] = m;
        if (idx < 4) {
            float z = lg[idx] * rms * s0 + base[idx];
            wts[idx] = 1.f / (1.f + expf(-z)) + EPS;
        } else if (idx < 8) {
            float z = lg[idx] * rms * s1 + base[idx];
            wts[idx] = 2.f / (1.f + expf(-z));
        }
    }
    __syncthreads();

    // Phase B: outputs straight from registers
    float pre[4], post[4], cmb[4][4];
#pragma unroll
    for (int k = 0; k < 4; ++k) { pre[k] = wts[k]; post[k] = wts[4 + k]; }
#pragma unroll
    for (int h = 0; h < 4; ++h)
#pragma unroll
        for (int k = 0; k < 4; ++k) cmb[h][k] = wts[8 + h * 4 + k];

#pragma unroll
    for (int dh = 0; dh < 2; ++dh) {
        const int dof = dh * 1024 + t * 4;
        float4 xk[4];
#pragma unroll
        for (int k = 0; k < 4; ++k) xk[k] = xr[2 * k + dh];
        float4 ov = *reinterpret_cast<const float4*>(outp + (size_t)bs * D_ + dof);
        float4 cv;
        cv.x = pre[0] * xk[0].x + pre[1] * xk[1].x + pre[2] * xk[2].x + pre[3] * xk[3].x;
        cv.y = pre[0] * xk[0].y + pre[1] * xk[1].y + pre[2] * xk[2].y + pre[3] * xk[3].y;
        cv.z = pre[0] * xk[0].z + pre[1] * xk[1].z + pre[2] * xk[2].z + pre[3] * xk[3].z;
        cv.w = pre[0] * xk[0].w + pre[1] * xk[1].w + pre[2] * xk[2].w + pre[3] * xk[3].w;
        *reinterpret_cast<float4*>(coll + (size_t)bs * D_ + dof) = cv;
#pragma unroll
        for (int h = 0; h < 4; ++h) {
            float4 yv;
            yv.x = post[h] * ov.x + cmb[h][0] * xk[0].x + cmb[h][1] * xk[1].x + cmb[h][2] * xk[2].x + cmb[h][3] * xk[3].x;
            yv.y = post[h] * ov.y + cmb[h][0] * xk[0].y + cmb[h][1] * xk[1].y + cmb[h][2] * xk[2].y + cmb[h][3] * xk[3].y;
            yv.z = post[h] * ov.z + cmb[h][0] * xk[0].z + cmb[h][1] * xk[1].z + cmb[h][2] * xk[2].z + cmb[h][3] * xk[3].z;
            yv.w = post[h] * ov.w + cmb[h][0] * xk[0].w + cmb[h][1] * xk[1].w + cmb[h][2] * xk[2].w + cmb[h][3] * xk[3].w;
            *reinterpret_cast<float4*>(y + (size_t)bs * KD + h * D_ + dof) = yv;
        }
    }
}

extern "C" void kernel_launch(void* const* d_in, const int* in_sizes, int n_in,
                              void* d_out, int out_size, void* d_ws, size_t ws_size,
                              hipStream_t stream) {
    const float* x     = (const float*)d_in[0];
    const float* outp  = (const float*)d_in[1];
    const float* W     = (const float*)d_in[2];
    const float* scale = (const float*)d_in[3];
    const float* base  = (const float*)d_in[4];
    float* y    = (float*)d_out;
    float* coll = y + (size_t)NTOK * KD;   // 67108864

    const size_t wb_bytes = (size_t)NOUT * KD * sizeof(unsigned short); // 384 KB
    if (ws_size >= wb_bytes) {
        unsigned short* Wb = (unsigned short*)d_ws;
        conv_w_kernel<<<NOUT * KD / (TPB * 4), TPB, 0, stream>>>(W, Wb);
        hypermix_kernel<true><<<NTOK, TPB, 0, stream>>>(x, outp, Wb, W, scale, base, y, coll);
    } else {
        hypermix_kernel<false><<<NTOK, TPB, 0, stream>>>(x, outp, nullptr, W, scale, base, y, coll);
    }
}

// Round 4
// 290.589 us; speedup vs baseline: 6.7100x; 2.3739x over previous
//
#include <hip/hip_runtime.h>

// HyperMixer fused kernel, MI355X (gfx950).
// x[B=2,S=4096,K=4,D=2048] f32, out[B,S,D] f32, W[24][8192] f32,
// scale[3], base[24]. Output = concat(y[B,S,K,D], collapsed[B,S,D]) f32.
//
// Round-4 design: one token per 256-thread block, x staged in LDS (f32,
// 32 KB) instead of registers (round-3: 208 VGPR -> 12% occupancy,
// latency-bound). Phase A splits the 24 projections across the 4 waves
// (6 rows each, 6 accumulators/thread). W is bf16 (L2-resident, 384 KB,
// converted once). Phase B re-reads x from LDS with conflict-free
// ds_read_b128. Target: <=128 VGPR -> 4 waves/SIMD, ~50% occupancy.

#define EPS 1e-6f
constexpr int K_ = 4, D_ = 2048, KD = 8192, NOUT = 24;
constexpr int NTOK = 2 * 4096;          // 8192 tokens
constexpr int TPB = 256;

static __device__ __forceinline__ unsigned short f2bf(float f) {
    unsigned int u = __float_as_uint(f);
    unsigned int r = (u + 0x7fffu + ((u >> 16) & 1u)) >> 16;
    return (unsigned short)r;
}

__global__ void conv_w_kernel(const float* __restrict__ W, unsigned short* __restrict__ Wb) {
    int i = (blockIdx.x * blockDim.x + threadIdx.x) * 4;
    float4 v = *reinterpret_cast<const float4*>(W + i);
    ushort4 u;
    u.x = f2bf(v.x); u.y = f2bf(v.y); u.z = f2bf(v.z); u.w = f2bf(v.w);
    *reinterpret_cast<ushort4*>(Wb + i) = u;
}

template <bool BW>
__global__ __launch_bounds__(TPB) void hypermix_kernel(
    const float* __restrict__ x, const float* __restrict__ outp,
    const unsigned short* __restrict__ Wb, const float* __restrict__ Wf,
    const float* __restrict__ scale, const float* __restrict__ base,
    float* __restrict__ y, float* __restrict__ coll)
{
    const int t = threadIdx.x;
    const int wave = t >> 6, lane = t & 63;
    const int bs = blockIdx.x;

    __shared__ float xs[KD];       // 32 KB staged token
    __shared__ float ssred[4];     // per-wave sumsq partials
    __shared__ float lg[NOUT];     // raw dot products
    __shared__ float wts[NOUT];    // 0..3 pre, 4..7 post, 8..23 comb[h][k]

    // ---- phase 0: stage x into LDS, per-wave sumsq ----
    {
        const float* xb = x + (size_t)bs * KD + t * 4;
        float ss = 0.f;
#pragma unroll
        for (int i = 0; i < 8; ++i) {
            float4 v = *reinterpret_cast<const float4*>(xb + i * 1024);
            *reinterpret_cast<float4*>(&xs[i * 1024 + t * 4]) = v;
            ss += v.x * v.x + v.y * v.y + v.z * v.z + v.w * v.w;
        }
#pragma unroll
        for (int m = 1; m < 64; m <<= 1) ss += __shfl_xor(ss, m, 64);
        if (lane == 0) ssred[wave] = ss;
    }
    __syncthreads();

    // ---- phase A: wave w computes dot rows 6w..6w+5 ----
    {
        float acc[6];
#pragma unroll
        for (int j = 0; j < 6; ++j) acc[j] = 0.f;
        const int obase = wave * 6;
        for (int it = 0; it < 32; ++it) {
            const int f = it * 256 + lane * 4;
            float4 xv = *reinterpret_cast<const float4*>(&xs[f]);
#pragma unroll
            for (int j = 0; j < 6; ++j) {
                float wx, wy, wz, ww;
                if (BW) {
                    uint2 u = *reinterpret_cast<const uint2*>(Wb + (obase + j) * KD + f);
                    wx = __uint_as_float(u.x << 16);
                    wy = __uint_as_float(u.x & 0xffff0000u);
                    wz = __uint_as_float(u.y << 16);
                    ww = __uint_as_float(u.y & 0xffff0000u);
                } else {
                    float4 w = *reinterpret_cast<const float4*>(Wf + (obase + j) * KD + f);
                    wx = w.x; wy = w.y; wz = w.z; ww = w.w;
                }
                acc[j] += xv.x * wx + xv.y * wy + xv.z * wz + xv.w * ww;
            }
        }
#pragma unroll
        for (int j = 0; j < 6; ++j) {
            float v = acc[j];
#pragma unroll
            for (int m = 1; m < 64; m <<= 1) v += __shfl_xor(v, m, 64);
            if (lane == 0) lg[obase + j] = v;
        }
    }
    __syncthreads();

    // ---- weights: 16 lanes, sigmoid/softmax/sinkhorn ----
    if (t < 16) {
        const int idx = t;                 // idx = h*4 + k
        float ss = ssred[0] + ssred[1] + ssred[2] + ssred[3];
        float rms = rsqrtf(ss * (1.f / 8192.f) + EPS);
        float s0 = scale[0], s1 = scale[1], s2 = scale[2];
        // comb logits; softmax over k (xor 1,2), +eps
        float cl = lg[8 + idx] * rms * s2 + base[8 + idx];
        float mx = fmaxf(cl, __shfl_xor(cl, 1, 64));
        mx = fmaxf(mx, __shfl_xor(mx, 2, 64));
        float e = expf(cl - mx);
        float se = e + __shfl_xor(e, 1, 64); se += __shfl_xor(se, 2, 64);
        float m = e / se + EPS;
        // sinkhorn: priming column norm (sum over h: xor 4,8), then 19x(row,col)
        float cs = m + __shfl_xor(m, 4, 64); cs += __shfl_xor(cs, 8, 64);
        m = m / (cs + EPS);
#pragma unroll
        for (int it = 0; it < 19; ++it) {
            float rs = m + __shfl_xor(m, 1, 64); rs += __shfl_xor(rs, 2, 64);
            m = m / (rs + EPS);
            cs = m + __shfl_xor(m, 4, 64); cs += __shfl_xor(cs, 8, 64);
            m = m / (cs + EPS);
        }
        wts[8 + idx] = m;
        if (idx < 4) {
            float z = lg[idx] * rms * s0 + base[idx];
            wts[idx] = 1.f / (1.f + expf(-z)) + EPS;
        } else if (idx < 8) {
            float z = lg[idx] * rms * s1 + base[idx];
            wts[idx] = 2.f / (1.f + expf(-z));
        }
    }
    __syncthreads();

    // ---- phase B: outputs from LDS x ----
    float pre[4], post[4], cmb[4][4];
#pragma unroll
    for (int k = 0; k < 4; ++k) { pre[k] = wts[k]; post[k] = wts[4 + k]; }
#pragma unroll
    for (int h = 0; h < 4; ++h)
#pragma unroll
        for (int k = 0; k < 4; ++k) cmb[h][k] = wts[8 + h * 4 + k];

#pragma unroll
    for (int dh = 0; dh < 2; ++dh) {
        const int dof = dh * 1024 + t * 4;
        float4 xk[4];
#pragma unroll
        for (int k = 0; k < 4; ++k)
            xk[k] = *reinterpret_cast<const float4*>(&xs[k * 2048 + dof]);
        float4 ov = *reinterpret_cast<const float4*>(outp + (size_t)bs * D_ + dof);
        float4 cv;
        cv.x = pre[0] * xk[0].x + pre[1] * xk[1].x + pre[2] * xk[2].x + pre[3] * xk[3].x;
        cv.y = pre[0] * xk[0].y + pre[1] * xk[1].y + pre[2] * xk[2].y + pre[3] * xk[3].y;
        cv.z = pre[0] * xk[0].z + pre[1] * xk[1].z + pre[2] * xk[2].z + pre[3] * xk[3].z;
        cv.w = pre[0] * xk[0].w + pre[1] * xk[1].w + pre[2] * xk[2].w + pre[3] * xk[3].w;
        *reinterpret_cast<float4*>(coll + (size_t)bs * D_ + dof) = cv;
#pragma unroll
        for (int h = 0; h < 4; ++h) {
            float4 yv;
            yv.x = post[h] * ov.x + cmb[h][0] * xk[0].x + cmb[h][1] * xk[1].x + cmb[h][2] * xk[2].x + cmb[h][3] * xk[3].x;
            yv.y = post[h] * ov.y + cmb[h][0] * xk[0].y + cmb[h][1] * xk[1].y + cmb[h][2] * xk[2].y + cmb[h][3] * xk[3].y;
            yv.z = post[h] * ov.z + cmb[h][0] * xk[0].z + cmb[h][1] * xk[1].z + cmb[h][2] * xk[2].z + cmb[h][3] * xk[3].z;
            yv.w = post[h] * ov.w + cmb[h][0] * xk[0].w + cmb[h][1] * xk[1].w + cmb[h][2] * xk[2].w + cmb[h][3] * xk[3].w;
            *reinterpret_cast<float4*>(y + (size_t)bs * KD + h * D_ + dof) = yv;
        }
    }
}

extern "C" void kernel_launch(void* const* d_in, const int* in_sizes, int n_in,
                              void* d_out, int out_size, void* d_ws, size_t ws_size,
                              hipStream_t stream) {
    const float* x     = (const float*)d_in[0];
    const float* outp  = (const float*)d_in[1];
    const float* W     = (const float*)d_in[2];
    const float* scale = (const float*)d_in[3];
    const float* base  = (const float*)d_in[4];
    float* y    = (float*)d_out;
    float* coll = y + (size_t)NTOK * KD;   // 67108864

    const size_t wb_bytes = (size_t)NOUT * KD * sizeof(unsigned short); // 384 KB
    if (ws_size >= wb_bytes) {
        unsigned short* Wb = (unsigned short*)d_ws;
        conv_w_kernel<<<NOUT * KD / (TPB * 4), TPB, 0, stream>>>(W, Wb);
        hypermix_kernel<true><<<NTOK, TPB, 0, stream>>>(x, outp, Wb, W, scale, base, y, coll);
    } else {
        hypermix_kernel<false><<<NTOK, TPB, 0, stream>>>(x, outp, nullptr, W, scale, base, y, coll);
    }
}